// Round 15
// baseline (14.166 us; speedup 1.0000x reference)
//
#include <hip/hip_runtime.h>
#include <hip/hip_bf16.h>
#include <math.h>

#define DD 64  // feature dim

typedef __bf16 bf16x8 __attribute__((ext_vector_type(8)));
typedef float f32x4 __attribute__((ext_vector_type(4)));

// Convert 8 fp32 -> bf16 fragment, accumulating sum of squares of the
// bf16-ROUNDED values into s (so d^2 = nx+ny-2dot = ||xb-yb||^2 >= 0).
__device__ inline bf16x8 cvt8n(const float4 a, const float4 b, float& s) {
  bf16x8 r;
  float t;
  r[0] = (__bf16)a.x; t = (float)r[0]; s = fmaf(t, t, s);
  r[1] = (__bf16)a.y; t = (float)r[1]; s = fmaf(t, t, s);
  r[2] = (__bf16)a.z; t = (float)r[2]; s = fmaf(t, t, s);
  r[3] = (__bf16)a.w; t = (float)r[3]; s = fmaf(t, t, s);
  r[4] = (__bf16)b.x; t = (float)r[4]; s = fmaf(t, t, s);
  r[5] = (__bf16)b.y; t = (float)r[5]; s = fmaf(t, t, s);
  r[6] = (__bf16)b.z; t = (float)r[6]; s = fmaf(t, t, s);
  r[7] = (__bf16)b.w; t = (float)r[7]; s = fmaf(t, t, s);
  return r;
}

// Fused CDist, drain-overlap geometry (between R13 and R14):
//   out[i][j] = sqrt(max(||xb_i||^2 + ||yb_j||^2 - 2 xb_i.yb_j, 0))
// 512 blocks of 128x64 -> 2 blocks/CU = 2 waves/SIMD: one wave's terminal
// nontemporal-store drain overlaps the other's compute (R14's 1 wave/SIMD
// had a bare ~1us drain). Waves stay fat: wave tile 64x32, 12 dwordx4-load
// burst, x-frags reused across 2 y-groups, 16 MFMAs, 8 nt stores.
// Swapped-operand MFMA: C/D row->j, col->i -> nontemporal float4 stores.
__global__ __launch_bounds__(256) void cdist_fused(
    const float* __restrict__ x, const float* __restrict__ y,
    float* __restrict__ out, int N, int M) {
  // Bijective XCD swizzle: 512 blocks, 8 XCDs -> 64 consecutive per XCD.
  const int bid = blockIdx.x;
  const int swz = (bid & 7) * 64 + (bid >> 3);
  const int bx = swz & 31;   // j tile (64 cols)
  const int by = swz >> 5;   // i tile (128 rows)

  const int lane = threadIdx.x & 63;
  const int wid  = threadIdx.x >> 6;      // 0..3
  const int wr = wid >> 1, wc = wid & 1;  // 2x2 wave grid
  const int i0 = by * 128 + wr * 64;      // wave's x-row base (64 rows)
  const int j0 = bx * 64 + wc * 32;       // wave's y-row base (32 rows)
  const int lrow = lane & 15;
  const int kgrp = lane >> 4;

  __shared__ float sny[4][32];  // per-wave y-norms [wid][n*16 + lrow]

  // Fragment loads (fp32 global -> bf16 regs) + partial norms.
  // A/B layout: lane l holds 8 contiguous k-elems of row (l&15) at k-offset
  // (l>>4)*8 (+32 per k-step). Verified rounds 2-14.
  bf16x8 a[4][2], b[2][2];
  float sa[4], sb[2];
  #pragma unroll
  for (int m = 0; m < 4; ++m) {
    const float* px = &x[(size_t)(i0 + m * 16 + lrow) * DD + kgrp * 8];
    sa[m] = 0.f;
    a[m][0] = cvt8n(*reinterpret_cast<const float4*>(px),
                    *reinterpret_cast<const float4*>(px + 4), sa[m]);
    a[m][1] = cvt8n(*reinterpret_cast<const float4*>(px + 32),
                    *reinterpret_cast<const float4*>(px + 36), sa[m]);
  }
  #pragma unroll
  for (int n = 0; n < 2; ++n) {
    const float* py = &y[(size_t)(j0 + n * 16 + lrow) * DD + kgrp * 8];
    sb[n] = 0.f;
    b[n][0] = cvt8n(*reinterpret_cast<const float4*>(py),
                    *reinterpret_cast<const float4*>(py + 4), sb[n]);
    b[n][1] = cvt8n(*reinterpret_cast<const float4*>(py + 32),
                    *reinterpret_cast<const float4*>(py + 36), sb[n]);
  }

  // Butterfly over kgrp bits: full norm of row (base + g*16 + lrow) per lane.
  #pragma unroll
  for (int m = 0; m < 4; ++m) {
    sa[m] += __shfl_xor(sa[m], 16, 64);
    sa[m] += __shfl_xor(sa[m], 32, 64);
  }
  #pragma unroll
  for (int n = 0; n < 2; ++n) {
    sb[n] += __shfl_xor(sb[n], 16, 64);
    sb[n] += __shfl_xor(sb[n], 32, 64);
  }

  // Publish y-norms to wave-private LDS (kgrp==0 lanes hold lrow = j-offset).
  if (kgrp == 0) {
    sny[wid][lrow]      = sb[0];
    sny[wid][16 + lrow] = sb[1];
  }

  // Swapped-operand MFMA: D[row -> j][col -> i]. 16 MFMAs.
  f32x4 acc[2][4] = {};  // acc[n][m]
  #pragma unroll
  for (int ks = 0; ks < 2; ++ks)
    #pragma unroll
    for (int n = 0; n < 2; ++n)
      #pragma unroll
      for (int m = 0; m < 4; ++m)
        acc[n][m] = __builtin_amdgcn_mfma_f32_16x16x32_bf16(
            b[n][ks], a[m][ks], acc[n][m], 0, 0, 0);

  // Epilogue: element (m, n, reg r): i = i0 + m*16 + lrow (x-norm = own
  // sa[m]); j = j0 + n*16 + kgrp*4 + r (y-norms: one float4 LDS read).
  #pragma unroll
  for (int n = 0; n < 2; ++n) {
    const float4 nyv =
        *reinterpret_cast<const float4*>(&sny[wid][n * 16 + kgrp * 4]);
    #pragma unroll
    for (int m = 0; m < 4; ++m) {
      f32x4 res;
      float d2;
      d2 = fmaf(-2.0f, acc[n][m][0], sa[m] + nyv.x);
      res[0] = __builtin_amdgcn_sqrtf(fmaxf(d2, 0.f));
      d2 = fmaf(-2.0f, acc[n][m][1], sa[m] + nyv.y);
      res[1] = __builtin_amdgcn_sqrtf(fmaxf(d2, 0.f));
      d2 = fmaf(-2.0f, acc[n][m][2], sa[m] + nyv.z);
      res[2] = __builtin_amdgcn_sqrtf(fmaxf(d2, 0.f));
      d2 = fmaf(-2.0f, acc[n][m][3], sa[m] + nyv.w);
      res[3] = __builtin_amdgcn_sqrtf(fmaxf(d2, 0.f));
      __builtin_nontemporal_store(
          res, reinterpret_cast<f32x4*>(
              &out[(size_t)(i0 + m * 16 + lrow) * M + j0 + n * 16 + kgrp * 4]));
    }
  }
}

extern "C" void kernel_launch(void* const* d_in, const int* in_sizes, int n_in,
                              void* d_out, int out_size, void* d_ws, size_t ws_size,
                              hipStream_t stream) {
  const float* x = (const float*)d_in[0];
  const float* y = (const float*)d_in[1];
  float* out = (float*)d_out;
  const int N = in_sizes[0] / DD;  // 2048
  const int M = in_sizes[1] / DD;  // 2048

  // 16 i-tiles x 32 j-tiles = 512 blocks = 2 per CU.
  const int nblocks = (N / 128) * (M / 64);
  cdist_fused<<<dim3(nblocks), dim3(256), 0, stream>>>(x, y, out, N, M);
}

// Round 16
// 13.972 us; speedup vs baseline: 1.0139x; 1.0139x over previous
//
#include <hip/hip_runtime.h>
#include <hip/hip_bf16.h>
#include <math.h>

#define DD 64  // feature dim

typedef __bf16 bf16x8 __attribute__((ext_vector_type(8)));
typedef float f32x4 __attribute__((ext_vector_type(4)));

// Convert 8 fp32 -> bf16 fragment, accumulating sum of squares of the
// bf16-ROUNDED values into s (so d^2 = nx+ny-2dot = ||xb-yb||^2 >= 0).
__device__ inline bf16x8 cvt8n(const float4 a, const float4 b, float& s) {
  bf16x8 r;
  float t;
  r[0] = (__bf16)a.x; t = (float)r[0]; s = fmaf(t, t, s);
  r[1] = (__bf16)a.y; t = (float)r[1]; s = fmaf(t, t, s);
  r[2] = (__bf16)a.z; t = (float)r[2]; s = fmaf(t, t, s);
  r[3] = (__bf16)a.w; t = (float)r[3]; s = fmaf(t, t, s);
  r[4] = (__bf16)b.x; t = (float)r[4]; s = fmaf(t, t, s);
  r[5] = (__bf16)b.y; t = (float)r[5]; s = fmaf(t, t, s);
  r[6] = (__bf16)b.z; t = (float)r[6]; s = fmaf(t, t, s);
  r[7] = (__bf16)b.w; t = (float)r[7]; s = fmaf(t, t, s);
  return r;
}

// Fused CDist: R14's block tile (128x128, 256 blocks = 1/CU, minimal 16x/16x
// input redundancy) but 512 threads = 8 waves -> 2 waves/SIMD, so one wave's
// compute overlaps the other's store drain (R15 conflated this lever with a
// worse block shape). Wave tile 64x32: 4 x-frag groups x 2 y-frag groups,
// 16 MFMAs, 12-dwordx4 load burst, 8 nontemporal float4 stores.
// Swapped-operand MFMA: C/D row->j, col->i -> contiguous float4 per lane.
__global__ __launch_bounds__(512) void cdist_fused(
    const float* __restrict__ x, const float* __restrict__ y,
    float* __restrict__ out, int N, int M) {
  // Bijective XCD swizzle: 256 blocks, 8 XCDs -> 32 consecutive per XCD.
  const int bid = blockIdx.x;
  const int swz = (bid & 7) * 32 + (bid >> 3);
  const int bx = swz & 15;   // j tile (128 cols)
  const int by = swz >> 4;   // i tile (128 rows)

  const int lane = threadIdx.x & 63;
  const int wid  = threadIdx.x >> 6;      // 0..7
  const int wr = wid >> 2, wc = wid & 3;  // 2x4 wave grid
  const int i0 = by * 128 + wr * 64;      // wave's x-row base (64 rows)
  const int j0 = bx * 128 + wc * 32;      // wave's y-row base (32 cols)
  const int lrow = lane & 15;
  const int kgrp = lane >> 4;

  __shared__ float sny[8][32];  // per-wave y-norms [wid][n*16 + lrow]

  // Fragment loads (fp32 global -> bf16 regs) + partial norms.
  // A/B layout: lane l holds 8 contiguous k-elems of row (l&15) at k-offset
  // (l>>4)*8 (+32 per k-step). Verified rounds 2-15.
  bf16x8 a[4][2], b[2][2];
  float sa[4], sb[2];
  #pragma unroll
  for (int m = 0; m < 4; ++m) {
    const float* px = &x[(size_t)(i0 + m * 16 + lrow) * DD + kgrp * 8];
    sa[m] = 0.f;
    a[m][0] = cvt8n(*reinterpret_cast<const float4*>(px),
                    *reinterpret_cast<const float4*>(px + 4), sa[m]);
    a[m][1] = cvt8n(*reinterpret_cast<const float4*>(px + 32),
                    *reinterpret_cast<const float4*>(px + 36), sa[m]);
  }
  #pragma unroll
  for (int n = 0; n < 2; ++n) {
    const float* py = &y[(size_t)(j0 + n * 16 + lrow) * DD + kgrp * 8];
    sb[n] = 0.f;
    b[n][0] = cvt8n(*reinterpret_cast<const float4*>(py),
                    *reinterpret_cast<const float4*>(py + 4), sb[n]);
    b[n][1] = cvt8n(*reinterpret_cast<const float4*>(py + 32),
                    *reinterpret_cast<const float4*>(py + 36), sb[n]);
  }

  // Butterfly over kgrp bits: full norm of row (base + g*16 + lrow) per lane.
  #pragma unroll
  for (int m = 0; m < 4; ++m) {
    sa[m] += __shfl_xor(sa[m], 16, 64);
    sa[m] += __shfl_xor(sa[m], 32, 64);
  }
  #pragma unroll
  for (int n = 0; n < 2; ++n) {
    sb[n] += __shfl_xor(sb[n], 16, 64);
    sb[n] += __shfl_xor(sb[n], 32, 64);
  }

  // Publish y-norms to wave-private LDS (kgrp==0 lanes hold lrow = j-offset).
  if (kgrp == 0) {
    sny[wid][lrow]      = sb[0];
    sny[wid][16 + lrow] = sb[1];
  }

  // Swapped-operand MFMA: D[row -> j][col -> i]. 16 MFMAs.
  f32x4 acc[2][4] = {};  // acc[n][m]
  #pragma unroll
  for (int ks = 0; ks < 2; ++ks)
    #pragma unroll
    for (int n = 0; n < 2; ++n)
      #pragma unroll
      for (int m = 0; m < 4; ++m)
        acc[n][m] = __builtin_amdgcn_mfma_f32_16x16x32_bf16(
            b[n][ks], a[m][ks], acc[n][m], 0, 0, 0);

  // Epilogue: element (m, n, reg r): i = i0 + m*16 + lrow (x-norm = own
  // sa[m]); j = j0 + n*16 + kgrp*4 + r (y-norms: one float4 LDS read).
  #pragma unroll
  for (int n = 0; n < 2; ++n) {
    const float4 nyv =
        *reinterpret_cast<const float4*>(&sny[wid][n * 16 + kgrp * 4]);
    #pragma unroll
    for (int m = 0; m < 4; ++m) {
      f32x4 res;
      float d2;
      d2 = fmaf(-2.0f, acc[n][m][0], sa[m] + nyv.x);
      res[0] = __builtin_amdgcn_sqrtf(fmaxf(d2, 0.f));
      d2 = fmaf(-2.0f, acc[n][m][1], sa[m] + nyv.y);
      res[1] = __builtin_amdgcn_sqrtf(fmaxf(d2, 0.f));
      d2 = fmaf(-2.0f, acc[n][m][2], sa[m] + nyv.z);
      res[2] = __builtin_amdgcn_sqrtf(fmaxf(d2, 0.f));
      d2 = fmaf(-2.0f, acc[n][m][3], sa[m] + nyv.w);
      res[3] = __builtin_amdgcn_sqrtf(fmaxf(d2, 0.f));
      __builtin_nontemporal_store(
          res, reinterpret_cast<f32x4*>(
              &out[(size_t)(i0 + m * 16 + lrow) * M + j0 + n * 16 + kgrp * 4]));
    }
  }
}

extern "C" void kernel_launch(void* const* d_in, const int* in_sizes, int n_in,
                              void* d_out, int out_size, void* d_ws, size_t ws_size,
                              hipStream_t stream) {
  const float* x = (const float*)d_in[0];
  const float* y = (const float*)d_in[1];
  float* out = (float*)d_out;
  const int N = in_sizes[0] / DD;  // 2048
  const int M = in_sizes[1] / DD;  // 2048

  // 16 x 16 tiles of 128x128 = 256 blocks = 1 per CU (8 waves each).
  const int nblocks = (N / 128) * (M / 128);
  cdist_fused<<<dim3(nblocks), dim3(512), 0, stream>>>(x, y, out, N, M);
}

// Round 17
// 13.899 us; speedup vs baseline: 1.0192x; 1.0053x over previous
//
#include <hip/hip_runtime.h>
#include <hip/hip_bf16.h>
#include <math.h>

#define DD 64  // feature dim

typedef __bf16 bf16x8 __attribute__((ext_vector_type(8)));
typedef float f32x4 __attribute__((ext_vector_type(4)));

// Convert 8 fp32 -> bf16 fragment, accumulating sum of squares of the
// bf16-ROUNDED values into s (so d^2 = nx+ny-2dot = ||xb-yb||^2 >= 0).
__device__ inline bf16x8 cvt8n(const float4 a, const float4 b, float& s) {
  bf16x8 r;
  float t;
  r[0] = (__bf16)a.x; t = (float)r[0]; s = fmaf(t, t, s);
  r[1] = (__bf16)a.y; t = (float)r[1]; s = fmaf(t, t, s);
  r[2] = (__bf16)a.z; t = (float)r[2]; s = fmaf(t, t, s);
  r[3] = (__bf16)a.w; t = (float)r[3]; s = fmaf(t, t, s);
  r[4] = (__bf16)b.x; t = (float)r[4]; s = fmaf(t, t, s);
  r[5] = (__bf16)b.y; t = (float)r[5]; s = fmaf(t, t, s);
  r[6] = (__bf16)b.z; t = (float)r[6]; s = fmaf(t, t, s);
  r[7] = (__bf16)b.w; t = (float)r[7]; s = fmaf(t, t, s);
  return r;
}

// Fused CDist, R14 geometry + STORE-EARLY interleave:
//   out[i][j] = sqrt(max(||xb_i||^2 + ||yb_j||^2 - 2 xb_i.yb_j, 0))
// 256 blocks of 128x128 = 1 block/CU; wave tile 64x64 (4x4 fragments).
// R16 showed extra TLP doesn't help -> the exposed cost is the terminal
// 4KB/wave store burst after all 32 MFMAs. Here the j-quadrants are
// computed AND stored one at a time (8 MFMAs -> 4 stores, x4), so the
// write stream starts ~4x earlier and the terminal drain shrinks ~4x.
// Also drops live acc regs 64->16 VGPRs.
// Swapped-operand MFMA: C/D row->j, col->i -> nontemporal float4 stores.
__global__ __launch_bounds__(256) void cdist_fused(
    const float* __restrict__ x, const float* __restrict__ y,
    float* __restrict__ out, int N, int M) {
  // Bijective XCD swizzle: 256 blocks, 8 XCDs -> 32 consecutive per XCD.
  const int bid = blockIdx.x;
  const int swz = (bid & 7) * 32 + (bid >> 3);
  const int bx = swz & 15;   // j tile (128 cols)
  const int by = swz >> 4;   // i tile (128 rows)

  const int lane = threadIdx.x & 63;
  const int wid  = threadIdx.x >> 6;      // 0..3
  const int wr = wid >> 1, wc = wid & 1;  // 2x2 wave grid
  const int i0 = by * 128 + wr * 64;      // wave's x-row base (64 rows)
  const int j0 = bx * 128 + wc * 64;      // wave's y-row base (64 cols)
  const int lrow = lane & 15;
  const int kgrp = lane >> 4;

  __shared__ float sny[4][64];  // per-wave y-norms [wid][n*16 + lrow]

  // Fragment loads (fp32 global -> bf16 regs) + partial norms.
  // A/B layout: lane l holds 8 contiguous k-elems of row (l&15) at k-offset
  // (l>>4)*8 (+32 per k-step). Verified rounds 2-16.
  bf16x8 a[4][2], b[4][2];
  float sa[4], sb[4];
  #pragma unroll
  for (int m = 0; m < 4; ++m) {
    const float* px = &x[(size_t)(i0 + m * 16 + lrow) * DD + kgrp * 8];
    sa[m] = 0.f;
    a[m][0] = cvt8n(*reinterpret_cast<const float4*>(px),
                    *reinterpret_cast<const float4*>(px + 4), sa[m]);
    a[m][1] = cvt8n(*reinterpret_cast<const float4*>(px + 32),
                    *reinterpret_cast<const float4*>(px + 36), sa[m]);
  }
  #pragma unroll
  for (int n = 0; n < 4; ++n) {
    const float* py = &y[(size_t)(j0 + n * 16 + lrow) * DD + kgrp * 8];
    sb[n] = 0.f;
    b[n][0] = cvt8n(*reinterpret_cast<const float4*>(py),
                    *reinterpret_cast<const float4*>(py + 4), sb[n]);
    b[n][1] = cvt8n(*reinterpret_cast<const float4*>(py + 32),
                    *reinterpret_cast<const float4*>(py + 36), sb[n]);
  }

  // Butterfly over kgrp bits: full norm of row (base + g*16 + lrow) per lane.
  #pragma unroll
  for (int m = 0; m < 4; ++m) {
    sa[m] += __shfl_xor(sa[m], 16, 64);
    sa[m] += __shfl_xor(sa[m], 32, 64);
  }
  #pragma unroll
  for (int n = 0; n < 4; ++n) {
    sb[n] += __shfl_xor(sb[n], 16, 64);
    sb[n] += __shfl_xor(sb[n], 32, 64);
  }

  // Publish y-norms to wave-private LDS (kgrp==0 lanes hold lrow = j-offset).
  if (kgrp == 0) {
    #pragma unroll
    for (int n = 0; n < 4; ++n) sny[wid][n * 16 + lrow] = sb[n];
  }

  // STORE-EARLY: per j-quadrant n -> 8 MFMAs, then 4 nt stores immediately.
  #pragma unroll
  for (int n = 0; n < 4; ++n) {
    f32x4 acc[4] = {};
    #pragma unroll
    for (int ks = 0; ks < 2; ++ks)
      #pragma unroll
      for (int m = 0; m < 4; ++m)
        acc[m] = __builtin_amdgcn_mfma_f32_16x16x32_bf16(
            b[n][ks], a[m][ks], acc[m], 0, 0, 0);

    const float4 nyv =
        *reinterpret_cast<const float4*>(&sny[wid][n * 16 + kgrp * 4]);
    #pragma unroll
    for (int m = 0; m < 4; ++m) {
      f32x4 res;
      float d2;
      d2 = fmaf(-2.0f, acc[m][0], sa[m] + nyv.x);
      res[0] = __builtin_amdgcn_sqrtf(fmaxf(d2, 0.f));
      d2 = fmaf(-2.0f, acc[m][1], sa[m] + nyv.y);
      res[1] = __builtin_amdgcn_sqrtf(fmaxf(d2, 0.f));
      d2 = fmaf(-2.0f, acc[m][2], sa[m] + nyv.z);
      res[2] = __builtin_amdgcn_sqrtf(fmaxf(d2, 0.f));
      d2 = fmaf(-2.0f, acc[m][3], sa[m] + nyv.w);
      res[3] = __builtin_amdgcn_sqrtf(fmaxf(d2, 0.f));
      __builtin_nontemporal_store(
          res, reinterpret_cast<f32x4*>(
              &out[(size_t)(i0 + m * 16 + lrow) * M + j0 + n * 16 + kgrp * 4]));
    }
  }
}

extern "C" void kernel_launch(void* const* d_in, const int* in_sizes, int n_in,
                              void* d_out, int out_size, void* d_ws, size_t ws_size,
                              hipStream_t stream) {
  const float* x = (const float*)d_in[0];
  const float* y = (const float*)d_in[1];
  float* out = (float*)d_out;
  const int N = in_sizes[0] / DD;  // 2048
  const int M = in_sizes[1] / DD;  // 2048

  // 16 x 16 tiles of 128x128 = 256 blocks = 1 per CU.
  const int nblocks = (N / 128) * (M / 128);
  cdist_fused<<<dim3(nblocks), dim3(256), 0, stream>>>(x, y, out, N, M);
}

// Round 18
// 13.490 us; speedup vs baseline: 1.0501x; 1.0303x over previous
//
#include <hip/hip_runtime.h>
#include <hip/hip_bf16.h>
#include <math.h>

#define DD 64  // feature dim

typedef __bf16 bf16x8 __attribute__((ext_vector_type(8)));
typedef float f32x4 __attribute__((ext_vector_type(4)));

// Convert 8 fp32 -> bf16 fragment, accumulating sum of squares of the
// bf16-ROUNDED values into s (so d^2 = nx+ny-2dot = ||xb-yb||^2 >= 0).
__device__ inline bf16x8 cvt8n(const float4 a, const float4 b, float& s) {
  bf16x8 r;
  float t;
  r[0] = (__bf16)a.x; t = (float)r[0]; s = fmaf(t, t, s);
  r[1] = (__bf16)a.y; t = (float)r[1]; s = fmaf(t, t, s);
  r[2] = (__bf16)a.z; t = (float)r[2]; s = fmaf(t, t, s);
  r[3] = (__bf16)a.w; t = (float)r[3]; s = fmaf(t, t, s);
  r[4] = (__bf16)b.x; t = (float)r[4]; s = fmaf(t, t, s);
  r[5] = (__bf16)b.y; t = (float)r[5]; s = fmaf(t, t, s);
  r[6] = (__bf16)b.z; t = (float)r[6]; s = fmaf(t, t, s);
  r[7] = (__bf16)b.w; t = (float)r[7]; s = fmaf(t, t, s);
  return r;
}

// Fused CDist, max work-per-wave geometry (best across R0-R17, 13.6us):
//   out[i][j] = sqrt(max(||xb_i||^2 + ||yb_j||^2 - 2 xb_i.yb_j, 0))
// 256 blocks of 128x128 -> exactly one block per CU (no scheduling tail).
// Each wave owns a 64x64 tile: 4x4 fragments, 32 MFMAs; x/y fragments are
// converted once and reused 4x. One wide independent load burst per wave
// (24 dwordx4/lane). Norms fold into the fp32->bf16 conversion; butterfly
// over kgrp lanes; y-norms exchanged via wave-private LDS.
// Swapped-operand MFMA: C/D row->j, col->i -> nontemporal float4 stores.
__global__ __launch_bounds__(256) void cdist_fused(
    const float* __restrict__ x, const float* __restrict__ y,
    float* __restrict__ out, int N, int M) {
  // Bijective XCD swizzle: 256 blocks, 8 XCDs -> 32 consecutive per XCD.
  const int bid = blockIdx.x;
  const int swz = (bid & 7) * 32 + (bid >> 3);
  const int bx = swz & 15;   // j tile (128 cols)
  const int by = swz >> 4;   // i tile (128 rows)

  const int lane = threadIdx.x & 63;
  const int wid  = threadIdx.x >> 6;      // 0..3
  const int wr = wid >> 1, wc = wid & 1;  // 2x2 wave grid
  const int i0 = by * 128 + wr * 64;      // wave's x-row base (64 rows)
  const int j0 = bx * 128 + wc * 64;      // wave's y-row base (64 cols)
  const int lrow = lane & 15;
  const int kgrp = lane >> 4;

  __shared__ float sny[4][64];  // per-wave y-norms [wid][n*16 + lrow]

  // Fragment loads (fp32 global -> bf16 regs) + partial norms.
  // A/B layout: lane l holds 8 contiguous k-elems of row (l&15) at k-offset
  // (l>>4)*8 (+32 per k-step). Verified rounds 2-17.
  bf16x8 a[4][2], b[4][2];
  float sa[4], sb[4];
  #pragma unroll
  for (int m = 0; m < 4; ++m) {
    const float* px = &x[(size_t)(i0 + m * 16 + lrow) * DD + kgrp * 8];
    sa[m] = 0.f;
    a[m][0] = cvt8n(*reinterpret_cast<const float4*>(px),
                    *reinterpret_cast<const float4*>(px + 4), sa[m]);
    a[m][1] = cvt8n(*reinterpret_cast<const float4*>(px + 32),
                    *reinterpret_cast<const float4*>(px + 36), sa[m]);
  }
  #pragma unroll
  for (int n = 0; n < 4; ++n) {
    const float* py = &y[(size_t)(j0 + n * 16 + lrow) * DD + kgrp * 8];
    sb[n] = 0.f;
    b[n][0] = cvt8n(*reinterpret_cast<const float4*>(py),
                    *reinterpret_cast<const float4*>(py + 4), sb[n]);
    b[n][1] = cvt8n(*reinterpret_cast<const float4*>(py + 32),
                    *reinterpret_cast<const float4*>(py + 36), sb[n]);
  }

  // Butterfly over kgrp bits: full norm of row (base + g*16 + lrow) per lane.
  #pragma unroll
  for (int m = 0; m < 4; ++m) {
    sa[m] += __shfl_xor(sa[m], 16, 64);
    sa[m] += __shfl_xor(sa[m], 32, 64);
  }
  #pragma unroll
  for (int n = 0; n < 4; ++n) {
    sb[n] += __shfl_xor(sb[n], 16, 64);
    sb[n] += __shfl_xor(sb[n], 32, 64);
  }

  // Publish y-norms to wave-private LDS (kgrp==0 lanes hold lrow = j-offset).
  if (kgrp == 0) {
    #pragma unroll
    for (int n = 0; n < 4; ++n) sny[wid][n * 16 + lrow] = sb[n];
  }

  // Swapped-operand MFMA: D[row -> j][col -> i]. 32 MFMAs.
  f32x4 acc[4][4] = {};  // acc[n][m]
  #pragma unroll
  for (int ks = 0; ks < 2; ++ks)
    #pragma unroll
    for (int n = 0; n < 4; ++n)
      #pragma unroll
      for (int m = 0; m < 4; ++m)
        acc[n][m] = __builtin_amdgcn_mfma_f32_16x16x32_bf16(
            b[n][ks], a[m][ks], acc[n][m], 0, 0, 0);

  // Epilogue: element (m, n, reg r): i = i0 + m*16 + lrow (x-norm = own
  // sa[m]); j = j0 + n*16 + kgrp*4 + r (y-norms: one float4 LDS read).
  #pragma unroll
  for (int n = 0; n < 4; ++n) {
    const float4 nyv =
        *reinterpret_cast<const float4*>(&sny[wid][n * 16 + kgrp * 4]);
    #pragma unroll
    for (int m = 0; m < 4; ++m) {
      f32x4 res;
      float d2;
      d2 = fmaf(-2.0f, acc[n][m][0], sa[m] + nyv.x);
      res[0] = __builtin_amdgcn_sqrtf(fmaxf(d2, 0.f));
      d2 = fmaf(-2.0f, acc[n][m][1], sa[m] + nyv.y);
      res[1] = __builtin_amdgcn_sqrtf(fmaxf(d2, 0.f));
      d2 = fmaf(-2.0f, acc[n][m][2], sa[m] + nyv.z);
      res[2] = __builtin_amdgcn_sqrtf(fmaxf(d2, 0.f));
      d2 = fmaf(-2.0f, acc[n][m][3], sa[m] + nyv.w);
      res[3] = __builtin_amdgcn_sqrtf(fmaxf(d2, 0.f));
      __builtin_nontemporal_store(
          res, reinterpret_cast<f32x4*>(
              &out[(size_t)(i0 + m * 16 + lrow) * M + j0 + n * 16 + kgrp * 4]));
    }
  }
}

extern "C" void kernel_launch(void* const* d_in, const int* in_sizes, int n_in,
                              void* d_out, int out_size, void* d_ws, size_t ws_size,
                              hipStream_t stream) {
  const float* x = (const float*)d_in[0];
  const float* y = (const float*)d_in[1];
  float* out = (float*)d_out;
  const int N = in_sizes[0] / DD;  // 2048
  const int M = in_sizes[1] / DD;  // 2048

  // 16 x 16 tiles of 128x128 = 256 blocks = 1 per CU.
  const int nblocks = (N / 128) * (M / 128);
  cdist_fused<<<dim3(nblocks), dim3(256), 0, stream>>>(x, y, out, N, M);
}